// Round 13
// baseline (204.952 us; speedup 1.0000x reference)
//
#include <hip/hip_runtime.h>
#include <hip/hip_bf16.h>

// HorizonTemporalSelfAttention: multi-scale deformable attention
// bs=2, nq=16384, E=256, NH=8, NL=4, NP=4, d=32, total tokens=21760
//
// R8:  XCD-aware sampler swizzle (taps L2-resident).
// R9 (REVERTED): broke intra-line coalescing -> 4x transactions, 3x time.
// R14/R16: level-split + split kernels + preamble softmax.
// R17: head-major vh: lines/point 4->3, sampler 79.5->62.3 us. Model
//      confirmed: sampler time ~ line-fill throughput.
// R18: paired-token layout (128B entry = [tok e | tok e+1], 2x mem): 2
//      fills/point always; 62.3->57.2 us. VALU issue (~40 us, 70% busy)
//      is now the binder -- coord math duplicated 4x across the c4 quad.
// R19: quad-dedup: lane c4 computes point p=c4's coords/weights/offsets
//      once; 6x ds_swizzle (DS pipe, not VALU) broadcasts {e0,e1,4 weight
//      half2s} per p. Bit-identical weights/blend order.
// R20: identical resubmit of R19 (previous round died on container
//      acquisition, not on the kernel).

typedef __attribute__((ext_vector_type(4))) float    float4v;
typedef __attribute__((ext_vector_type(2))) float    float2v;
typedef __attribute__((ext_vector_type(8))) _Float16 half8;
typedef __attribute__((ext_vector_type(4))) _Float16 half4;
typedef __attribute__((ext_vector_type(2))) _Float16 half2v;

#define NQ    16384
#define NTOK  21760
#define LREC  48          // halves per (b,h,q) record: 32 off | 16 logits

#define GEMM_BLOCKS 768   // 256 M-tiles x 3 N-tiles
#define CONV_BLOCKS 5440  // 16 hb-slices x 340 token-tiles of 64
#define SLICE_H 1392704   // halves per pair-slice: (NTOK+1)*64 (incl. front pad)

union H8 { half8 v; half2v p[4]; };
union HU { half2v h; unsigned u; };

// ---------------- K-G: logit GEMM (unchanged) ----------------
#define LDSTR 88
__global__ __launch_bounds__(256) void gemm_kernel(
    const float* __restrict__ qf,
    const float* __restrict__ Woff, const float* __restrict__ Wattn,
    const float* __restrict__ boff, const float* __restrict__ battn,
    _Float16* __restrict__ lh) {
  const int tid = threadIdx.x;

  __shared__ _Float16 As[128 * LDSTR];
  __shared__ _Float16 Bs[128 * LDSTR];

  const int lane = tid & 63;
  const int wv   = tid >> 6;
  const int wm   = wv >> 1, wn = wv & 1;
  const int quad = lane >> 4;
  const int r    = lane & 15;
  const int blockM = (blockIdx.x & 255) * 128;
  const int n0     = (blockIdx.x >> 8) * 128;

  float4v acc[4][4];
#pragma unroll
  for (int i = 0; i < 4; ++i)
#pragma unroll
    for (int j = 0; j < 4; ++j) acc[i][j] = (float4v){0.f, 0.f, 0.f, 0.f};

  for (int kc = 0; kc < 4; ++kc) {
    const int k0 = kc * 64;
    if (kc) __syncthreads();
#pragma unroll
    for (int it = 0; it < 8; ++it) {
      int idx = it * 256 + tid;
      int row = idx >> 4, k4 = idx & 15;
      float4v v = *(const float4v*)(qf + (size_t)(blockM + row) * 256 + k0 + k4 * 4);
      half4 o;
      o[0] = (_Float16)v[0]; o[1] = (_Float16)v[1];
      o[2] = (_Float16)v[2]; o[3] = (_Float16)v[3];
      *(half4*)&As[row * LDSTR + k4 * 4] = o;
    }
#pragma unroll
    for (int it = 0; it < 8; ++it) {
      int idx = it * 256 + tid;
      int row = idx >> 4, k4 = idx & 15;
      int n = n0 + row;
      const float* src = (n < 256) ? (Woff + (size_t)n * 256)
                                   : (Wattn + (size_t)(n - 256) * 256);
      float4v v = *(const float4v*)(src + k0 + k4 * 4);
      half4 o;
      o[0] = (_Float16)v[0]; o[1] = (_Float16)v[1];
      o[2] = (_Float16)v[2]; o[3] = (_Float16)v[3];
      *(half4*)&Bs[row * LDSTR + k4 * 4] = o;
    }
    __syncthreads();

#pragma unroll
    for (int kf = 0; kf < 2; ++kf) {
      const int ko = kf * 32 + quad * 8;
      half8 af[4], bf[4];
#pragma unroll
      for (int mi = 0; mi < 4; ++mi)
        af[mi] = *(const half8*)&As[(wm * 64 + mi * 16 + r) * LDSTR + ko];
#pragma unroll
      for (int ni = 0; ni < 4; ++ni)
        bf[ni] = *(const half8*)&Bs[(wn * 64 + ni * 16 + r) * LDSTR + ko];
#pragma unroll
      for (int mi = 0; mi < 4; ++mi)
#pragma unroll
        for (int ni = 0; ni < 4; ++ni)
          acc[mi][ni] = __builtin_amdgcn_mfma_f32_16x16x32_f16(af[mi], bf[ni], acc[mi][ni], 0, 0, 0);
    }
  }

#pragma unroll
  for (int mi = 0; mi < 4; ++mi) {
    const int mb = blockM + wm * 64 + mi * 16 + quad * 4;
#pragma unroll
    for (int ni = 0; ni < 4; ++ni) {
      const int n = n0 + wn * 64 + ni * 16 + r;
      const float bias = (n < 256) ? boff[n] : battn[n - 256];
      const int h    = (n < 256) ? (n >> 5) : ((n - 256) >> 4);
      const int slot = (n < 256) ? (n & 31) : (32 + ((n - 256) & 15));
#pragma unroll
      for (int reg = 0; reg < 4; ++reg) {
        const int bq = mb + reg;
        const int b = bq >> 14, q = bq & 16383;
        lh[((size_t)(b * 8 + h) * NQ + q) * LREC + slot] =
            (_Float16)(acc[mi][ni][reg] + bias);
      }
    }
  }
}

// ---------------- K-C (pair): convert + paired-token transpose ----------------
// vh pair layout per slice: [64h front pad][entry 0..21759, 64h each]
// entry e = [token e (32h) | token e+1 (32h)].
__global__ __launch_bounds__(256) void conv_pair_kernel(
    const float* __restrict__ val, _Float16* __restrict__ vh) {
  const int bid   = blockIdx.x;
  const int xcd   = bid & 7;
  const int local = bid >> 3;                 // 0..679
  const int sl    = (local >= 340) ? 1 : 0;
  const int hb    = xcd * 2 + sl;             // 0..15 == b*8+h
  const int tokT  = local - sl * 340;
  const int tid   = threadIdx.x;
  const int c8    = tid & 3;
  const int tok   = tokT * 64 + (tid >> 2);
  const int b     = hb >> 3, h = hb & 7;

  const float* src = val + ((size_t)b * NTOK + tok) * 256 + h * 32 + c8 * 8;
  float4v v0 = *(const float4v*)src;
  float4v v1 = *(const float4v*)(src + 4);
  half8 o;
  o[0] = (_Float16)v0[0]; o[1] = (_Float16)v0[1];
  o[2] = (_Float16)v0[2]; o[3] = (_Float16)v0[3];
  o[4] = (_Float16)v1[0]; o[5] = (_Float16)v1[1];
  o[6] = (_Float16)v1[2]; o[7] = (_Float16)v1[3];

  _Float16* sd = vh + (size_t)hb * SLICE_H + 64;   // slice data (entry 0)
  *(half8*)(sd + (size_t)tok * 64 + c8 * 8)      = o;  // entry tok, half0
  *(half8*)(sd + (size_t)tok * 64 - 32 + c8 * 8) = o;  // entry tok-1, half1
  if (tok == 0) {
    half8 z;
#pragma unroll
    for (int k = 0; k < 8; ++k) z[k] = (_Float16)0;
    *(half8*)(sd - 64 + c8 * 8) = z;                   // front pad half0
  }
  if (tok == NTOK - 1) {
    half8 z;
#pragma unroll
    for (int k = 0; k < 8; ++k) z[k] = (_Float16)0;
    *(half8*)(sd + (size_t)NTOK * 64 - 32 + c8 * 8) = z; // entry 21759 half1
  }
}

// ---------------- K-S (pair): sampling, quad-dedup'd coord math ----------------
// grid 16384 flat; xcd = bid&7, local = bid>>3, hb = xcd*2 + (local>>10),
// qt = local&1023. thread: c4 = tid&3 (channels AND own point), l, qi.
// Lane c4 computes point p=c4's coords/weights/entry-offsets once; per-p
// ds_swizzle (j = (i&0x1C)|p, DS pipe) broadcasts them to the quad.
__global__ __launch_bounds__(256) void sample_pair_kernel(
    const _Float16* __restrict__ vh, const float* __restrict__ refp,
    const _Float16* __restrict__ lh, float* __restrict__ out) {
  const int bid   = blockIdx.x;
  const int xcd   = bid & 7;
  const int local = bid >> 3;
  const int hb    = xcd * 2 + (local >> 10);  // 0..15, == b*8+h
  const int qt    = local & 1023;
  const int h     = hb & 7;
  const int b     = hb >> 3;
  const int tid = threadIdx.x;

  // ---- preamble: softmax once per query, shared via LDS ----
  __shared__ _Float16 wsm[16][16];
  {
    const int q16  = tid >> 4;
    const int slot = tid & 15;
    const float lg = (float)lh[((size_t)hb * NQ + qt * 16 + q16) * LREC + 32 + slot];
    float m = lg;
    m = fmaxf(m, __shfl_xor(m, 1));
    m = fmaxf(m, __shfl_xor(m, 2));
    m = fmaxf(m, __shfl_xor(m, 4));
    m = fmaxf(m, __shfl_xor(m, 8));
    const float e = __expf(lg - m);
    float s = e;
    s += __shfl_xor(s, 1);
    s += __shfl_xor(s, 2);
    s += __shfl_xor(s, 4);
    s += __shfl_xor(s, 8);
    wsm[q16][slot] = (_Float16)(e * (1.0f / s));
  }
  __syncthreads();

  const int c4 = tid & 3;
  const int l  = (tid >> 2) & 3;
  const int qi = tid >> 4;                    // 0..15
  const int q  = qt * 16 + qi;
  const size_t bq = (size_t)b * NQ + q;
  const _Float16* rec = lh + ((size_t)hb * NQ + q) * LREC;

  // level geometry (quad-uniform: same l across the quad)
  const int   W    = 128 >> l;
  const float fW   = (float)W;
  const int   base = (l == 0) ? 0 : (l == 1) ? 16384 : (l == 2) ? 20480 : 21504;

  // ---- own point p = c4: coords + weights + entry offsets, computed once ----
  const float a    = (float)wsm[qi][l * 4 + c4];
  const half2v ohp = *(const half2v*)(rec + l * 8 + c4 * 2);   // own 2 offsets
  const float2v rp = *(const float2v*)(refp + bq * 8 + c4 * 2);
  const float ox = (float)ohp[0];
  const float oy = (float)ohp[1];
  // (ref + off/shape)*2-1 through grid_sample == ref*W + off - 0.5
  const float x = rp[0] * fW + ox - 0.5f;
  const float y = rp[1] * fW + oy - 0.5f;
  const float xf = floorf(x), yf = floorf(y);
  const float fx = x - xf, fy = y - yf;
  const int ix = (int)xf, iy = (int)yf;
  // pair anchor: entry (iy*W + ax) holds tokens (ax, ax+1); clamp [-1, W-1].
  const int ax  = min(max(ix, -1), W - 1);
  const int iy0 = min(max(iy, 0), W - 1);
  const int iy1 = min(max(iy + 1, 0), W - 1);
  const float wx0 = ((unsigned)ix       < (unsigned)W) ? 1.f - fx : 0.f;
  const float wx1 = ((unsigned)(ix + 1) < (unsigned)W) ? fx       : 0.f;
  const float wy0 = ((unsigned)iy       < (unsigned)W) ? 1.f - fy : 0.f;
  const float wy1 = ((unsigned)(iy + 1) < (unsigned)W) ? fy       : 0.f;
  const _Float16 w00 = (_Float16)(a * wx0 * wy0);
  const _Float16 w01 = (_Float16)(a * wx1 * wy0);
  const _Float16 w10 = (_Float16)(a * wx0 * wy1);
  const _Float16 w11 = (_Float16)(a * wx1 * wy1);
  HU u00, u01, u10, u11;
  u00.h = (half2v){w00, w00};
  u01.h = (half2v){w01, w01};
  u10.h = (half2v){w10, w10};
  u11.h = (half2v){w11, w11};
  // byte offsets from slice start (front pad = entry 0 of the raw slice);
  // +1 bias keeps them non-negative (ax = -1 -> 0). Max ~2.79 MB, fits u32.
  const unsigned e0 = (unsigned)(1 + base + iy0 * W + ax) * 128u;
  const unsigned e1 = (unsigned)(1 + base + iy1 * W + ax) * 128u;

  // own-lane channel base within the slice
  const char* sb = (const char*)(vh + (size_t)hb * SLICE_H) + c4 * 16;

  half2v accl0 = (half2v){(_Float16)0, (_Float16)0};
  half2v accl1 = (half2v){(_Float16)0, (_Float16)0};
  half2v accl2 = (half2v){(_Float16)0, (_Float16)0};
  half2v accl3 = (half2v){(_Float16)0, (_Float16)0};

  // per point p: 6 ds_swizzle broadcasts (bit-mode and=0x1C, or=p) + 4 taps
#define POINT(P) {                                                           \
    const int ctl = 0x1C | ((P) << 5);                                       \
    const unsigned be0 = (unsigned)__builtin_amdgcn_ds_swizzle((int)e0, ctl);\
    const unsigned be1 = (unsigned)__builtin_amdgcn_ds_swizzle((int)e1, ctl);\
    HU b00, b01, b10, b11;                                                   \
    b00.u = (unsigned)__builtin_amdgcn_ds_swizzle((int)u00.u, ctl);          \
    b01.u = (unsigned)__builtin_amdgcn_ds_swizzle((int)u01.u, ctl);          \
    b10.u = (unsigned)__builtin_amdgcn_ds_swizzle((int)u10.u, ctl);          \
    b11.u = (unsigned)__builtin_amdgcn_ds_swizzle((int)u11.u, ctl);          \
    const _Float16* e0p = (const _Float16*)(sb + be0);                       \
    const _Float16* e1p = (const _Float16*)(sb + be1);                       \
    H8 t00, t01, t10, t11;                                                   \
    t00.v = *(const half8*)(e0p);                                            \
    t01.v = *(const half8*)(e0p + 32);                                       \
    t10.v = *(const half8*)(e1p);                                            \
    t11.v = *(const half8*)(e1p + 32);                                       \
    accl0 += b00.h * t00.p[0] + b01.h * t01.p[0]                             \
           + b10.h * t10.p[0] + b11.h * t11.p[0];                            \
    accl1 += b00.h * t00.p[1] + b01.h * t01.p[1]                             \
           + b10.h * t10.p[1] + b11.h * t11.p[1];                            \
    accl2 += b00.h * t00.p[2] + b01.h * t01.p[2]                             \
           + b10.h * t10.p[2] + b11.h * t11.p[2];                            \
    accl3 += b00.h * t00.p[3] + b01.h * t01.p[3]                             \
           + b10.h * t10.p[3] + b11.h * t11.p[3];                            \
  }
  POINT(0)
  POINT(1)
  POINT(2)
  POINT(3)
#undef POINT

  float acc0[4], acc1[4];
  acc0[0] = (float)accl0[0]; acc0[1] = (float)accl0[1];
  acc0[2] = (float)accl1[0]; acc0[3] = (float)accl1[1];
  acc1[0] = (float)accl2[0]; acc1[1] = (float)accl2[1];
  acc1[2] = (float)accl3[0]; acc1[3] = (float)accl3[1];

  __shared__ float sm[4][16][33];
#pragma unroll
  for (int j = 0; j < 4; ++j) {
    sm[l][qi][c4 * 8 + j]     = acc0[j];
    sm[l][qi][c4 * 8 + 4 + j] = acc1[j];
  }
  __syncthreads();
  const size_t obase = ((size_t)b * 256 + h * 32) * NQ + qt * 16;
#pragma unroll
  for (int i = 0; i < 2; ++i) {
    const int idx = i * 256 + tid;
    const int c  = idx >> 4;
    const int ql = idx & 15;
    const float v = ((sm[0][ql][c] + sm[1][ql][c]) + sm[2][ql][c]) + sm[3][ql][c];
    out[obase + (size_t)c * NQ + ql] = v;
  }
}

// ---------------- Fallback path (R17, proven): single-copy head-major ----------
__global__ __launch_bounds__(256) void conv_kernel(
    const float* __restrict__ val, _Float16* __restrict__ vh) {
  const int bid   = blockIdx.x;
  const int xcd   = bid & 7;
  const int local = bid >> 3;
  const int sl    = (local >= 340) ? 1 : 0;
  const int hb    = xcd * 2 + sl;
  const int tokT  = local - sl * 340;
  const int tid   = threadIdx.x;
  const int c8    = tid & 3;
  const int tok   = tokT * 64 + (tid >> 2);
  const int b     = hb >> 3, h = hb & 7;

  const float* src = val + ((size_t)b * NTOK + tok) * 256 + h * 32 + c8 * 8;
  float4v v0 = *(const float4v*)src;
  float4v v1 = *(const float4v*)(src + 4);
  half8 o;
  o[0] = (_Float16)v0[0]; o[1] = (_Float16)v0[1];
  o[2] = (_Float16)v0[2]; o[3] = (_Float16)v0[3];
  o[4] = (_Float16)v1[0]; o[5] = (_Float16)v1[1];
  o[6] = (_Float16)v1[2]; o[7] = (_Float16)v1[3];
  *(half8*)(vh + ((size_t)hb * NTOK + tok) * 32 + c8 * 8) = o;
}

__global__ __launch_bounds__(256) void sample_kernel(
    const _Float16* __restrict__ vh, const float* __restrict__ refp,
    const _Float16* __restrict__ lh, float* __restrict__ out) {
  const int bid   = blockIdx.x;
  const int xcd   = bid & 7;
  const int local = bid >> 3;
  const int hb    = xcd * 2 + (local >> 10);
  const int qt    = local & 1023;
  const int h     = hb & 7;
  const int b     = hb >> 3;
  const int tid = threadIdx.x;

  __shared__ _Float16 wsm[16][16];
  {
    const int q16  = tid >> 4;
    const int slot = tid & 15;
    const float lg = (float)lh[((size_t)hb * NQ + qt * 16 + q16) * LREC + 32 + slot];
    float m = lg;
    m = fmaxf(m, __shfl_xor(m, 1));
    m = fmaxf(m, __shfl_xor(m, 2));
    m = fmaxf(m, __shfl_xor(m, 4));
    m = fmaxf(m, __shfl_xor(m, 8));
    const float e = __expf(lg - m);
    float s = e;
    s += __shfl_xor(s, 1);
    s += __shfl_xor(s, 2);
    s += __shfl_xor(s, 4);
    s += __shfl_xor(s, 8);
    wsm[q16][slot] = (_Float16)(e * (1.0f / s));
  }
  __syncthreads();

  const int c4 = tid & 3;
  const int l  = (tid >> 2) & 3;
  const int qi = tid >> 4;
  const int q  = qt * 16 + qi;
  const size_t bq = (size_t)b * NQ + q;
  const _Float16* rec = lh + ((size_t)hb * NQ + q) * LREC;

  const half8 oh = *(const half8*)(rec + l * 8);
  const half4 ownw = *(const half4*)&wsm[qi][l * 4];

  float4v rp0 = *(const float4v*)(refp + bq * 8);
  float4v rp1 = *(const float4v*)(refp + bq * 8 + 4);
  const float rpx[4] = {rp0[0], rp0[2], rp1[0], rp1[2]};
  const float rpy[4] = {rp0[1], rp0[3], rp1[1], rp1[3]};

  const int   W    = 128 >> l;
  const float fW   = (float)W;
  const int   base = (l == 0) ? 0 : (l == 1) ? 16384 : (l == 2) ? 20480 : 21504;
  const _Float16* vlev = vh + ((size_t)hb * NTOK + base) * 32 + c4 * 8;

  half2v accl0 = (half2v){(_Float16)0, (_Float16)0};
  half2v accl1 = (half2v){(_Float16)0, (_Float16)0};
  half2v accl2 = (half2v){(_Float16)0, (_Float16)0};
  half2v accl3 = (half2v){(_Float16)0, (_Float16)0};

#pragma unroll
  for (int p = 0; p < 4; ++p) {
    const float a  = (float)ownw[p];
    const float ox = (float)oh[p * 2];
    const float oy = (float)oh[p * 2 + 1];
    const float x = rpx[p] * fW + ox - 0.5f;
    const float y = rpy[p] * fW + oy - 0.5f;
    const float xf = floorf(x), yf = floorf(y);
    const float fx = x - xf, fy = y - yf;
    const int ix = (int)xf, iy = (int)yf;
    const int ix0 = min(max(ix, 0), W - 1);
    const int ix1 = min(max(ix + 1, 0), W - 1);
    const int iy0 = min(max(iy, 0), W - 1);
    const int iy1 = min(max(iy + 1, 0), W - 1);
    const float wx0 = ((unsigned)ix       < (unsigned)W) ? 1.f - fx : 0.f;
    const float wx1 = ((unsigned)(ix + 1) < (unsigned)W) ? fx       : 0.f;
    const float wy0 = ((unsigned)iy       < (unsigned)W) ? 1.f - fy : 0.f;
    const float wy1 = ((unsigned)(iy + 1) < (unsigned)W) ? fy       : 0.f;
    const _Float16 w00 = (_Float16)(a * wx0 * wy0);
    const _Float16 w01 = (_Float16)(a * wx1 * wy0);
    const _Float16 w10 = (_Float16)(a * wx0 * wy1);
    const _Float16 w11 = (_Float16)(a * wx1 * wy1);
    const half2v h00 = (half2v){w00, w00};
    const half2v h01 = (half2v){w01, w01};
    const half2v h10 = (half2v){w10, w10};
    const half2v h11 = (half2v){w11, w11};
    const _Float16* r0 = vlev + (size_t)(iy0 * W) * 32;
    const _Float16* r1 = vlev + (size_t)(iy1 * W) * 32;
    H8 t00, t01, t10, t11;
    t00.v = *(const half8*)(r0 + ix0 * 32);
    t01.v = *(const half8*)(r0 + ix1 * 32);
    t10.v = *(const half8*)(r1 + ix0 * 32);
    t11.v = *(const half8*)(r1 + ix1 * 32);
    accl0 += h00 * t00.p[0] + h01 * t01.p[0] + h10 * t10.p[0] + h11 * t11.p[0];
    accl1 += h00 * t00.p[1] + h01 * t01.p[1] + h10 * t10.p[1] + h11 * t11.p[1];
    accl2 += h00 * t00.p[2] + h01 * t01.p[2] + h10 * t10.p[2] + h11 * t11.p[2];
    accl3 += h00 * t00.p[3] + h01 * t01.p[3] + h10 * t10.p[3] + h11 * t11.p[3];
  }

  float acc0[4], acc1[4];
  acc0[0] = (float)accl0[0]; acc0[1] = (float)accl0[1];
  acc0[2] = (float)accl1[0]; acc0[3] = (float)accl1[1];
  acc1[0] = (float)accl2[0]; acc1[1] = (float)accl2[1];
  acc1[2] = (float)accl3[0]; acc1[3] = (float)accl3[1];

  __shared__ float sm[4][16][33];
#pragma unroll
  for (int j = 0; j < 4; ++j) {
    sm[l][qi][c4 * 8 + j]     = acc0[j];
    sm[l][qi][c4 * 8 + 4 + j] = acc1[j];
  }
  __syncthreads();
  const size_t obase = ((size_t)b * 256 + h * 32) * NQ + qt * 16;
#pragma unroll
  for (int i = 0; i < 2; ++i) {
    const int idx = i * 256 + tid;
    const int c  = idx >> 4;
    const int ql = idx & 15;
    const float v = ((sm[0][ql][c] + sm[1][ql][c]) + sm[2][ql][c]) + sm[3][ql][c];
    out[obase + (size_t)c * NQ + ql] = v;
  }
}

extern "C" void kernel_launch(void* const* d_in, const int* in_sizes, int n_in,
                              void* d_out, int out_size, void* d_ws, size_t ws_size,
                              hipStream_t stream) {
  const float* query = (const float*)d_in[0];
  const float* value = (const float*)d_in[1];
  const float* refp  = (const float*)d_in[2];
  const float* Woff  = (const float*)d_in[3];
  const float* boff  = (const float*)d_in[4];
  const float* Wattn = (const float*)d_in[5];
  const float* battn = (const float*)d_in[6];
  float* out = (float*)d_out;

  char* ws = (char*)d_ws;
  const size_t PAIR_VH_BYTES = (size_t)16 * SLICE_H * 2;   // 44,566,528
  const size_t LH_BYTES      = 25165824;

  if (ws_size >= PAIR_VH_BYTES + LH_BYTES) {
    _Float16* vh = (_Float16*)ws;
    _Float16* lh = (_Float16*)(ws + PAIR_VH_BYTES);
    gemm_kernel<<<GEMM_BLOCKS, 256, 0, stream>>>(
        query, Woff, Wattn, boff, battn, lh);
    conv_pair_kernel<<<CONV_BLOCKS, 256, 0, stream>>>(value, vh);
    sample_pair_kernel<<<16384, 256, 0, stream>>>(vh, refp, lh, out);
  } else {
    _Float16* vh = (_Float16*)ws;                    // 22,282,240 B
    _Float16* lh = (_Float16*)(ws + 22282240);
    gemm_kernel<<<GEMM_BLOCKS, 256, 0, stream>>>(
        query, Woff, Wattn, boff, battn, lh);
    conv_kernel<<<CONV_BLOCKS, 256, 0, stream>>>(value, vh);
    sample_kernel<<<16384, 256, 0, stream>>>(vh, refp, lh, out);
  }
}

// Round 14
// 202.899 us; speedup vs baseline: 1.0101x; 1.0101x over previous
//
#include <hip/hip_runtime.h>
#include <hip/hip_bf16.h>

// HorizonTemporalSelfAttention: multi-scale deformable attention
// bs=2, nq=16384, E=256, NH=8, NL=4, NP=4, d=32, total tokens=21760
//
// R8:  XCD-aware sampler swizzle (taps L2-resident).
// R9 (REVERTED): broke intra-line coalescing -> 4x transactions, 3x time.
// R17: head-major vh: sampler 79.5->62.3. Model: line-fill throughput bound.
// R18: paired-token layout (128B entry = [tok e|tok e+1]): 2 fills/point,
//      sampler 57.2 us. BEST sampler.
// R19/R20 (REVERTED): quad-dedup via ds_swizzle: VALU 70->45% but dur +2us
//      -> VALU was NOT the binder; memory pipe saturated. Sampler is at its
//      structural floor (~57 us, occupancy 74%, minimum fills/point).
// R21: attack the GEMM (est. 40-50 us, floor ~15): epilogue was 64 scattered
//      scalar f16 stores/thread (12.6M TA transactions). Now: LDS-bounce the
//      output tile (reuse As/Bs after sync) and write 8 quad-coalesced 16B
//      vector stores/thread (4 lanes = one 64B segment). Bit-identical values.

typedef __attribute__((ext_vector_type(4))) float    float4v;
typedef __attribute__((ext_vector_type(2))) float    float2v;
typedef __attribute__((ext_vector_type(8))) _Float16 half8;
typedef __attribute__((ext_vector_type(4))) _Float16 half4;
typedef __attribute__((ext_vector_type(2))) _Float16 half2v;

#define NQ    16384
#define NTOK  21760
#define LREC  48          // halves per (b,h,q) record: 32 off | 16 logits

#define GEMM_BLOCKS 768   // 256 M-tiles x 3 N-tiles
#define CONV_BLOCKS 5440  // 16 hb-slices x 340 token-tiles of 64
#define SLICE_H 1392704   // halves per pair-slice: (NTOK+1)*64 (incl. front pad)

union H8 { half8 v; half2v p[4]; };

// ---------------- K-G: logit GEMM (LDS-bounce epilogue) ----------------
#define LDSTR 88
#define OSTR  136         // epilogue row stride (halves): 272B, 16B-aligned rows
__global__ __launch_bounds__(256) void gemm_kernel(
    const float* __restrict__ qf,
    const float* __restrict__ Woff, const float* __restrict__ Wattn,
    const float* __restrict__ boff, const float* __restrict__ battn,
    _Float16* __restrict__ lh) {
  const int tid = threadIdx.x;

  __shared__ _Float16 smem[128 * LDSTR * 2];   // As | Bs; reused as out-tile
  _Float16* As = smem;
  _Float16* Bs = smem + 128 * LDSTR;

  const int lane = tid & 63;
  const int wv   = tid >> 6;
  const int wm   = wv >> 1, wn = wv & 1;
  const int quad = lane >> 4;
  const int r    = lane & 15;
  const int blockM = (blockIdx.x & 255) * 128;
  const int n0     = (blockIdx.x >> 8) * 128;

  float4v acc[4][4];
#pragma unroll
  for (int i = 0; i < 4; ++i)
#pragma unroll
    for (int j = 0; j < 4; ++j) acc[i][j] = (float4v){0.f, 0.f, 0.f, 0.f};

  for (int kc = 0; kc < 4; ++kc) {
    const int k0 = kc * 64;
    if (kc) __syncthreads();
    // A: 128 rows x 16 float4 k-cols, f32 -> f16
#pragma unroll
    for (int it = 0; it < 8; ++it) {
      int idx = it * 256 + tid;
      int row = idx >> 4, k4 = idx & 15;
      float4v v = *(const float4v*)(qf + (size_t)(blockM + row) * 256 + k0 + k4 * 4);
      half4 o;
      o[0] = (_Float16)v[0]; o[1] = (_Float16)v[1];
      o[2] = (_Float16)v[2]; o[3] = (_Float16)v[3];
      *(half4*)&As[row * LDSTR + k4 * 4] = o;
    }
    // B: 128 rows x 16 float4 k-cols from Wcat f32 (L2-resident, 394 KB)
#pragma unroll
    for (int it = 0; it < 8; ++it) {
      int idx = it * 256 + tid;
      int row = idx >> 4, k4 = idx & 15;
      int n = n0 + row;
      const float* src = (n < 256) ? (Woff + (size_t)n * 256)
                                   : (Wattn + (size_t)(n - 256) * 256);
      float4v v = *(const float4v*)(src + k0 + k4 * 4);
      half4 o;
      o[0] = (_Float16)v[0]; o[1] = (_Float16)v[1];
      o[2] = (_Float16)v[2]; o[3] = (_Float16)v[3];
      *(half4*)&Bs[row * LDSTR + k4 * 4] = o;
    }
    __syncthreads();

#pragma unroll
    for (int kf = 0; kf < 2; ++kf) {
      const int ko = kf * 32 + quad * 8;
      half8 af[4], bf[4];
#pragma unroll
      for (int mi = 0; mi < 4; ++mi)
        af[mi] = *(const half8*)&As[(wm * 64 + mi * 16 + r) * LDSTR + ko];
#pragma unroll
      for (int ni = 0; ni < 4; ++ni)
        bf[ni] = *(const half8*)&Bs[(wn * 64 + ni * 16 + r) * LDSTR + ko];
#pragma unroll
      for (int mi = 0; mi < 4; ++mi)
#pragma unroll
        for (int ni = 0; ni < 4; ++ni)
          acc[mi][ni] = __builtin_amdgcn_mfma_f32_16x16x32_f16(af[mi], bf[ni], acc[mi][ni], 0, 0, 0);
    }
  }

  // ---- epilogue: stage f16 tile in LDS, then quad-coalesced 16B stores ----
  __syncthreads();   // all As/Bs reads done -> safe to reuse smem
#pragma unroll
  for (int mi = 0; mi < 4; ++mi) {
    const int q0 = wm * 64 + mi * 16 + quad * 4;
#pragma unroll
    for (int ni = 0; ni < 4; ++ni) {
      const int col = wn * 64 + ni * 16 + r;
      const int n = n0 + col;
      const float bias = (n < 256) ? boff[n] : battn[n - 256];
#pragma unroll
      for (int reg = 0; reg < 4; ++reg)
        smem[(q0 + reg) * OSTR + col] = (_Float16)(acc[mi][ni][reg] + bias);
    }
  }
  __syncthreads();

  const int b   = blockM >> 14;
  const int qq0 = blockM & 16383;
  if (n0 < 256) {
    // offsets tile: h = h_base + (col>>5), slot = col&31 (64B piece per (h,q))
    const int h_base = n0 >> 5;   // 0 or 4
#pragma unroll
    for (int i = 0; i < 8; ++i) {
      const int idx = i * 256 + tid;        // 2048 pieces of 16B
      const int q   = idx >> 4;
      const int rem = idx & 15;
      const int hl  = rem >> 2;
      const int j   = rem & 3;              // lanes 0-3: 64B contiguous
      half8 v = *(const half8*)&smem[q * OSTR + hl * 32 + j * 8];
      *(half8*)&lh[((size_t)(b * 8 + h_base + hl) * NQ + qq0 + q) * LREC + j * 8] = v;
    }
  } else {
    // attn tile: h = col>>4, slot = 32 + (col&15) (32B piece per (h,q))
#pragma unroll
    for (int i = 0; i < 8; ++i) {
      const int idx = i * 256 + tid;
      const int q   = idx >> 4;
      const int rem = idx & 15;
      const int hl  = rem >> 1;
      const int j   = rem & 1;              // lane pairs: 32B contiguous
      half8 v = *(const half8*)&smem[q * OSTR + hl * 16 + j * 8];
      *(half8*)&lh[((size_t)(b * 8 + hl) * NQ + qq0 + q) * LREC + 32 + j * 8] = v;
    }
  }
}

// ---------------- K-C (pair): convert + paired-token transpose ----------------
// vh pair layout per slice: [64h front pad][entry 0..21759, 64h each]
// entry e = [token e (32h) | token e+1 (32h)].
__global__ __launch_bounds__(256) void conv_pair_kernel(
    const float* __restrict__ val, _Float16* __restrict__ vh) {
  const int bid   = blockIdx.x;
  const int xcd   = bid & 7;
  const int local = bid >> 3;                 // 0..679
  const int sl    = (local >= 340) ? 1 : 0;
  const int hb    = xcd * 2 + sl;             // 0..15 == b*8+h
  const int tokT  = local - sl * 340;
  const int tid   = threadIdx.x;
  const int c8    = tid & 3;
  const int tok   = tokT * 64 + (tid >> 2);
  const int b     = hb >> 3, h = hb & 7;

  const float* src = val + ((size_t)b * NTOK + tok) * 256 + h * 32 + c8 * 8;
  float4v v0 = *(const float4v*)src;
  float4v v1 = *(const float4v*)(src + 4);
  half8 o;
  o[0] = (_Float16)v0[0]; o[1] = (_Float16)v0[1];
  o[2] = (_Float16)v0[2]; o[3] = (_Float16)v0[3];
  o[4] = (_Float16)v1[0]; o[5] = (_Float16)v1[1];
  o[6] = (_Float16)v1[2]; o[7] = (_Float16)v1[3];

  _Float16* sd = vh + (size_t)hb * SLICE_H + 64;   // slice data (entry 0)
  *(half8*)(sd + (size_t)tok * 64 + c8 * 8)      = o;  // entry tok, half0
  *(half8*)(sd + (size_t)tok * 64 - 32 + c8 * 8) = o;  // entry tok-1, half1
  if (tok == 0) {
    half8 z;
#pragma unroll
    for (int k = 0; k < 8; ++k) z[k] = (_Float16)0;
    *(half8*)(sd - 64 + c8 * 8) = z;                   // front pad half0
  }
  if (tok == NTOK - 1) {
    half8 z;
#pragma unroll
    for (int k = 0; k < 8; ++k) z[k] = (_Float16)0;
    *(half8*)(sd + (size_t)NTOK * 64 - 32 + c8 * 8) = z; // entry 21759 half1
  }
}

// ---------------- K-S (pair): sampling (R18 form, swizzle reverted) ----------
__global__ __launch_bounds__(256) void sample_pair_kernel(
    const _Float16* __restrict__ vh, const float* __restrict__ refp,
    const _Float16* __restrict__ lh, float* __restrict__ out) {
  const int bid   = blockIdx.x;
  const int xcd   = bid & 7;
  const int local = bid >> 3;
  const int hb    = xcd * 2 + (local >> 10);  // 0..15, == b*8+h
  const int qt    = local & 1023;
  const int h     = hb & 7;
  const int b     = hb >> 3;
  const int tid = threadIdx.x;

  // ---- preamble: softmax once per query, shared via LDS ----
  __shared__ _Float16 wsm[16][16];
  {
    const int q16  = tid >> 4;
    const int slot = tid & 15;
    const float lg = (float)lh[((size_t)hb * NQ + qt * 16 + q16) * LREC + 32 + slot];
    float m = lg;
    m = fmaxf(m, __shfl_xor(m, 1));
    m = fmaxf(m, __shfl_xor(m, 2));
    m = fmaxf(m, __shfl_xor(m, 4));
    m = fmaxf(m, __shfl_xor(m, 8));
    const float e = __expf(lg - m);
    float s = e;
    s += __shfl_xor(s, 1);
    s += __shfl_xor(s, 2);
    s += __shfl_xor(s, 4);
    s += __shfl_xor(s, 8);
    wsm[q16][slot] = (_Float16)(e * (1.0f / s));
  }
  __syncthreads();

  const int c4 = tid & 3;
  const int l  = (tid >> 2) & 3;
  const int qi = tid >> 4;                    // 0..15
  const int q  = qt * 16 + qi;
  const size_t bq = (size_t)b * NQ + q;
  const _Float16* rec = lh + ((size_t)hb * NQ + q) * LREC;

  const half8 oh = *(const half8*)(rec + l * 8);
  const half4 ownw = *(const half4*)&wsm[qi][l * 4];

  float4v rp0 = *(const float4v*)(refp + bq * 8);
  float4v rp1 = *(const float4v*)(refp + bq * 8 + 4);
  const float rpx[4] = {rp0[0], rp0[2], rp1[0], rp1[2]};
  const float rpy[4] = {rp0[1], rp0[3], rp1[1], rp1[3]};

  const int   W    = 128 >> l;
  const float fW   = (float)W;
  const int   base = (l == 0) ? 0 : (l == 1) ? 16384 : (l == 2) ? 20480 : 21504;
  // pair layout: entry stride 64 halves; vlev points at entry(base), own slice
  const _Float16* vlev = vh + (size_t)hb * SLICE_H + 64 + (size_t)base * 64 + c4 * 8;

  half2v accl0 = (half2v){(_Float16)0, (_Float16)0};
  half2v accl1 = (half2v){(_Float16)0, (_Float16)0};
  half2v accl2 = (half2v){(_Float16)0, (_Float16)0};
  half2v accl3 = (half2v){(_Float16)0, (_Float16)0};

#pragma unroll
  for (int p = 0; p < 4; ++p) {
    const float a  = (float)ownw[p];
    const float ox = (float)oh[p * 2];
    const float oy = (float)oh[p * 2 + 1];
    const float x = rpx[p] * fW + ox - 0.5f;
    const float y = rpy[p] * fW + oy - 0.5f;
    const float xf = floorf(x), yf = floorf(y);
    const float fx = x - xf, fy = y - yf;
    const int ix = (int)xf, iy = (int)yf;
    // pair anchor: entry (iy*W + ax) holds tokens (ax, ax+1); clamp [-1, W-1].
    const int ax  = min(max(ix, -1), W - 1);
    const int iy0 = min(max(iy, 0), W - 1);
    const int iy1 = min(max(iy + 1, 0), W - 1);
    const float wx0 = ((unsigned)ix       < (unsigned)W) ? 1.f - fx : 0.f;
    const float wx1 = ((unsigned)(ix + 1) < (unsigned)W) ? fx       : 0.f;
    const float wy0 = ((unsigned)iy       < (unsigned)W) ? 1.f - fy : 0.f;
    const float wy1 = ((unsigned)(iy + 1) < (unsigned)W) ? fy       : 0.f;
    const _Float16 w00 = (_Float16)(a * wx0 * wy0);
    const _Float16 w01 = (_Float16)(a * wx1 * wy0);
    const _Float16 w10 = (_Float16)(a * wx0 * wy1);
    const _Float16 w11 = (_Float16)(a * wx1 * wy1);
    const half2v h00 = (half2v){w00, w00};
    const half2v h01 = (half2v){w01, w01};
    const half2v h10 = (half2v){w10, w10};
    const half2v h11 = (half2v){w11, w11};
    // one 128B entry per row: t00 = half0, t01 = half1 (+32h imm offset)
    const _Float16* e0 = vlev + (iy0 * W + ax) * 64;
    const _Float16* e1 = vlev + (iy1 * W + ax) * 64;
    H8 t00, t01, t10, t11;
    t00.v = *(const half8*)(e0);
    t01.v = *(const half8*)(e0 + 32);
    t10.v = *(const half8*)(e1);
    t11.v = *(const half8*)(e1 + 32);
    accl0 += h00 * t00.p[0] + h01 * t01.p[0] + h10 * t10.p[0] + h11 * t11.p[0];
    accl1 += h00 * t00.p[1] + h01 * t01.p[1] + h10 * t10.p[1] + h11 * t11.p[1];
    accl2 += h00 * t00.p[2] + h01 * t01.p[2] + h10 * t10.p[2] + h11 * t11.p[2];
    accl3 += h00 * t00.p[3] + h01 * t01.p[3] + h10 * t10.p[3] + h11 * t11.p[3];
  }

  float acc0[4], acc1[4];
  acc0[0] = (float)accl0[0]; acc0[1] = (float)accl0[1];
  acc0[2] = (float)accl1[0]; acc0[3] = (float)accl1[1];
  acc1[0] = (float)accl2[0]; acc1[1] = (float)accl2[1];
  acc1[2] = (float)accl3[0]; acc1[3] = (float)accl3[1];

  __shared__ float sm[4][16][33];
#pragma unroll
  for (int j = 0; j < 4; ++j) {
    sm[l][qi][c4 * 8 + j]     = acc0[j];
    sm[l][qi][c4 * 8 + 4 + j] = acc1[j];
  }
  __syncthreads();
  const size_t obase = ((size_t)b * 256 + h * 32) * NQ + qt * 16;
#pragma unroll
  for (int i = 0; i < 2; ++i) {
    const int idx = i * 256 + tid;
    const int c  = idx >> 4;
    const int ql = idx & 15;
    const float v = ((sm[0][ql][c] + sm[1][ql][c]) + sm[2][ql][c]) + sm[3][ql][c];
    out[obase + (size_t)c * NQ + ql] = v;
  }
}

// ---------------- Fallback path (R17, proven): single-copy head-major ----------
__global__ __launch_bounds__(256) void conv_kernel(
    const float* __restrict__ val, _Float16* __restrict__ vh) {
  const int bid   = blockIdx.x;
  const int xcd   = bid & 7;
  const int local = bid >> 3;
  const int sl    = (local >= 340) ? 1 : 0;
  const int hb    = xcd * 2 + sl;
  const int tokT  = local - sl * 340;
  const int tid   = threadIdx.x;
  const int c8    = tid & 3;
  const int tok   = tokT * 64 + (tid >> 2);
  const int b     = hb >> 3, h = hb & 7;

  const float* src = val + ((size_t)b * NTOK + tok) * 256 + h * 32 + c8 * 8;
  float4v v0 = *(const float4v*)src;
  float4v v1 = *(const float4v*)(src + 4);
  half8 o;
  o[0] = (_Float16)v0[0]; o[1] = (_Float16)v0[1];
  o[2] = (_Float16)v0[2]; o[3] = (_Float16)v0[3];
  o[4] = (_Float16)v1[0]; o[5] = (_Float16)v1[1];
  o[6] = (_Float16)v1[2]; o[7] = (_Float16)v1[3];
  *(half8*)(vh + ((size_t)hb * NTOK + tok) * 32 + c8 * 8) = o;
}

__global__ __launch_bounds__(256) void sample_kernel(
    const _Float16* __restrict__ vh, const float* __restrict__ refp,
    const _Float16* __restrict__ lh, float* __restrict__ out) {
  const int bid   = blockIdx.x;
  const int xcd   = bid & 7;
  const int local = bid >> 3;
  const int hb    = xcd * 2 + (local >> 10);
  const int qt    = local & 1023;
  const int h     = hb & 7;
  const int b     = hb >> 3;
  const int tid = threadIdx.x;

  __shared__ _Float16 wsm[16][16];
  {
    const int q16  = tid >> 4;
    const int slot = tid & 15;
    const float lg = (float)lh[((size_t)hb * NQ + qt * 16 + q16) * LREC + 32 + slot];
    float m = lg;
    m = fmaxf(m, __shfl_xor(m, 1));
    m = fmaxf(m, __shfl_xor(m, 2));
    m = fmaxf(m, __shfl_xor(m, 4));
    m = fmaxf(m, __shfl_xor(m, 8));
    const float e = __expf(lg - m);
    float s = e;
    s += __shfl_xor(s, 1);
    s += __shfl_xor(s, 2);
    s += __shfl_xor(s, 4);
    s += __shfl_xor(s, 8);
    wsm[q16][slot] = (_Float16)(e * (1.0f / s));
  }
  __syncthreads();

  const int c4 = tid & 3;
  const int l  = (tid >> 2) & 3;
  const int qi = tid >> 4;
  const int q  = qt * 16 + qi;
  const size_t bq = (size_t)b * NQ + q;
  const _Float16* rec = lh + ((size_t)hb * NQ + q) * LREC;

  const half8 oh = *(const half8*)(rec + l * 8);
  const half4 ownw = *(const half4*)&wsm[qi][l * 4];

  float4v rp0 = *(const float4v*)(refp + bq * 8);
  float4v rp1 = *(const float4v*)(refp + bq * 8 + 4);
  const float rpx[4] = {rp0[0], rp0[2], rp1[0], rp1[2]};
  const float rpy[4] = {rp0[1], rp0[3], rp1[1], rp1[3]};

  const int   W    = 128 >> l;
  const float fW   = (float)W;
  const int   base = (l == 0) ? 0 : (l == 1) ? 16384 : (l == 2) ? 20480 : 21504;
  const _Float16* vlev = vh + ((size_t)hb * NTOK + base) * 32 + c4 * 8;

  half2v accl0 = (half2v){(_Float16)0, (_Float16)0};
  half2v accl1 = (half2v){(_Float16)0, (_Float16)0};
  half2v accl2 = (half2v){(_Float16)0, (_Float16)0};
  half2v accl3 = (half2v){(_Float16)0, (_Float16)0};

#pragma unroll
  for (int p = 0; p < 4; ++p) {
    const float a  = (float)ownw[p];
    const float ox = (float)oh[p * 2];
    const float oy = (float)oh[p * 2 + 1];
    const float x = rpx[p] * fW + ox - 0.5f;
    const float y = rpy[p] * fW + oy - 0.5f;
    const float xf = floorf(x), yf = floorf(y);
    const float fx = x - xf, fy = y - yf;
    const int ix = (int)xf, iy = (int)yf;
    const int ix0 = min(max(ix, 0), W - 1);
    const int ix1 = min(max(ix + 1, 0), W - 1);
    const int iy0 = min(max(iy, 0), W - 1);
    const int iy1 = min(max(iy + 1, 0), W - 1);
    const float wx0 = ((unsigned)ix       < (unsigned)W) ? 1.f - fx : 0.f;
    const float wx1 = ((unsigned)(ix + 1) < (unsigned)W) ? fx       : 0.f;
    const float wy0 = ((unsigned)iy       < (unsigned)W) ? 1.f - fy : 0.f;
    const float wy1 = ((unsigned)(iy + 1) < (unsigned)W) ? fy       : 0.f;
    const _Float16 w00 = (_Float16)(a * wx0 * wy0);
    const _Float16 w01 = (_Float16)(a * wx1 * wy0);
    const _Float16 w10 = (_Float16)(a * wx0 * wy1);
    const _Float16 w11 = (_Float16)(a * wx1 * wy1);
    const half2v h00 = (half2v){w00, w00};
    const half2v h01 = (half2v){w01, w01};
    const half2v h10 = (half2v){w10, w10};
    const half2v h11 = (half2v){w11, w11};
    const _Float16* r0 = vlev + (size_t)(iy0 * W) * 32;
    const _Float16* r1 = vlev + (size_t)(iy1 * W) * 32;
    H8 t00, t01, t10, t11;
    t00.v = *(const half8*)(r0 + ix0 * 32);
    t01.v = *(const half8*)(r0 + ix1 * 32);
    t10.v = *(const half8*)(r1 + ix0 * 32);
    t11.v = *(const half8*)(r1 + ix1 * 32);
    accl0 += h00 * t00.p[0] + h01 * t01.p[0] + h10 * t10.p[0] + h11 * t11.p[0];
    accl1 += h00 * t00.p[1] + h01 * t01.p[1] + h10 * t10.p[1] + h11 * t11.p[1];
    accl2 += h00 * t00.p[2] + h01 * t01.p[2] + h10 * t10.p[2] + h11 * t11.p[2];
    accl3 += h00 * t00.p[3] + h01 * t01.p[3] + h10 * t10.p[3] + h11 * t11.p[3];
  }

  float acc0[4], acc1[4];
  acc0[0] = (float)accl0[0]; acc0[1] = (float)accl0[1];
  acc0[2] = (float)accl1[0]; acc0[3] = (float)accl1[1];
  acc1[0] = (float)accl2[0]; acc1[1] = (float)accl2[1];
  acc1[2] = (float)accl3[0]; acc1[3] = (float)accl3[1];

  __shared__ float sm[4][16][33];
#pragma unroll
  for (int j = 0; j < 4; ++j) {
    sm[l][qi][c4 * 8 + j]     = acc0[j];
    sm[l][qi][c4 * 8 + 4 + j] = acc1[j];
  }
  __syncthreads();
  const size_t obase = ((size_t)b * 256 + h * 32) * NQ + qt * 16;
#pragma unroll
  for (int i = 0; i < 2; ++i) {
    const int idx = i * 256 + tid;
    const int c  = idx >> 4;
    const int ql = idx & 15;
    const float v = ((sm[0][ql][c] + sm[1][ql][c]) + sm[2][ql][c]) + sm[3][ql][c];
    out[obase + (size_t)c * NQ + ql] = v;
  }
}

extern "C" void kernel_launch(void* const* d_in, const int* in_sizes, int n_in,
                              void* d_out, int out_size, void* d_ws, size_t ws_size,
                              hipStream_t stream) {
  const float* query = (const float*)d_in[0];
  const float* value = (const float*)d_in[1];
  const float* refp  = (const float*)d_in[2];
  const float* Woff  = (const float*)d_in[3];
  const float* boff  = (const float*)d_in[4];
  const float* Wattn = (const float*)d_in[5];
  const float* battn = (const float*)d_in[6];
  float* out = (float*)d_out;

  char* ws = (char*)d_ws;
  const size_t PAIR_VH_BYTES = (size_t)16 * SLICE_H * 2;   // 44,566,528
  const size_t LH_BYTES      = 25165824;

  if (ws_size >= PAIR_VH_BYTES + LH_BYTES) {
    _Float16* vh = (_Float16*)ws;
    _Float16* lh = (_Float16*)(ws + PAIR_VH_BYTES);
    gemm_kernel<<<GEMM_BLOCKS, 256, 0, stream>>>(
        query, Woff, Wattn, boff, battn, lh);
    conv_pair_kernel<<<CONV_BLOCKS, 256, 0, stream>>>(value, vh);
    sample_pair_kernel<<<16384, 256, 0, stream>>>(vh, refp, lh, out);
  } else {
    _Float16* vh = (_Float16*)ws;                    // 22,282,240 B
    _Float16* lh = (_Float16*)(ws + 22282240);
    gemm_kernel<<<GEMM_BLOCKS, 256, 0, stream>>>(
        query, Woff, Wattn, boff, battn, lh);
    conv_kernel<<<CONV_BLOCKS, 256, 0, stream>>>(value, vh);
    sample_kernel<<<16384, 256, 0, stream>>>(vh, refp, lh, out);
  }
}